// Round 1
// baseline (488.789 us; speedup 1.0000x reference)
//
#include <hip/hip_runtime.h>

// MultiHeadAttn fused block, MI355X/gfx950.
// Pipeline: cvt f32->bf16 -> 3x proj GEMM (bf16 MFMA) -> flash attn -> add+LN
//           -> out GEMM (+bias+relu) -> add+LN -> f32 out.
// ws layout (bytes), S = 8192*1024*2 = 16,777,216:
//   [0,S)   qb   (later reused as attb)
//   [S,2S)  kb   (later reused as h1b)
//   [2S,3S) vb   (later reused as h2b)
//   [3S,4S) qpb  [4S,5S) kpb  [5S,6S) vpb
//   [6S, 6S+8MB) Wq/Wk/Wv/Wo bf16
// total ~104 MB.

typedef __attribute__((ext_vector_type(4))) float f32x4;
typedef __attribute__((ext_vector_type(8))) short s16x8;
typedef __attribute__((ext_vector_type(4))) short s16x4;

__device__ __forceinline__ unsigned short f2bf(float f) {
  union { float f; unsigned u; } x; x.f = f;
  unsigned r = x.u + 0x7fffu + ((x.u >> 16) & 1u);
  return (unsigned short)(r >> 16);
}
__device__ __forceinline__ float bf2f(unsigned short h) {
  union { unsigned u; float f; } x; x.u = ((unsigned)h) << 16;
  return x.f;
}

__device__ __forceinline__ void gload_lds16(const void* g, void* l) {
  __builtin_amdgcn_global_load_lds(
      (const __attribute__((address_space(1))) unsigned int*)g,
      (__attribute__((address_space(3))) unsigned int*)l, 16, 0, 0);
}

__global__ __launch_bounds__(256) void cvt_f32_bf16(
    const float* __restrict__ src, unsigned short* __restrict__ dst, int n4) {
  int i = blockIdx.x * blockDim.x + threadIdx.x;
  if (i >= n4) return;
  float4 f = reinterpret_cast<const float4*>(src)[i];
  s16x4 o;
  o[0] = (short)f2bf(f.x); o[1] = (short)f2bf(f.y);
  o[2] = (short)f2bf(f.z); o[3] = (short)f2bf(f.w);
  reinterpret_cast<s16x4*>(dst)[i] = o;
}

// C[M,N] = A[M,K] @ B[N,K]^T, all bf16 (C bf16 out), optional bias+relu epilogue.
// 128x128 tile, BK=32, 4 waves (2x2), 4x4 16x16x32 frags per wave.
template<int RELU_BIAS>
__global__ __launch_bounds__(256) void gemm_bt(
    const unsigned short* __restrict__ A, const unsigned short* __restrict__ B,
    unsigned short* __restrict__ C, const float* __restrict__ bias,
    int M, int N, int K) {
  __shared__ __align__(16) unsigned short As[128 * 32];
  __shared__ __align__(16) unsigned short Bs[128 * 32];
  const int tid = threadIdx.x;
  const int lane = tid & 63;
  const int w = tid >> 6;
  const int brow = blockIdx.x * 128;
  const int bcol = blockIdx.y * 128;
  const int wr = (w >> 1) * 64;
  const int wc = (w & 1) * 64;

  f32x4 acc[4][4] = {};

  const int srow = w * 32 + (lane >> 2);  // + j*16
  const int scol = (lane & 3) * 8;
  const int rfrag = lane & 15;
  const int kfrag = (lane >> 4) * 8;

  for (int k0 = 0; k0 < K; k0 += 32) {
    __syncthreads();
#pragma unroll
    for (int j = 0; j < 2; ++j) {
      const unsigned short* ga = A + (size_t)(brow + srow + j * 16) * K + k0 + scol;
      gload_lds16(ga, As + (w * 1024 + j * 512));
      const unsigned short* gb = B + (size_t)(bcol + srow + j * 16) * K + k0 + scol;
      gload_lds16(gb, Bs + (w * 1024 + j * 512));
    }
    asm volatile("s_waitcnt vmcnt(0)" ::: "memory");
    __syncthreads();
    s16x8 a[4], b[4];
#pragma unroll
    for (int m = 0; m < 4; ++m)
      a[m] = *(const s16x8*)(As + (wr + m * 16 + rfrag) * 32 + kfrag);
#pragma unroll
    for (int n = 0; n < 4; ++n)
      b[n] = *(const s16x8*)(Bs + (wc + n * 16 + rfrag) * 32 + kfrag);
#pragma unroll
    for (int m = 0; m < 4; ++m)
#pragma unroll
      for (int n = 0; n < 4; ++n)
        acc[m][n] = __builtin_amdgcn_mfma_f32_16x16x32_bf16(a[m], b[n], acc[m][n], 0, 0, 0);
  }

  const int crow = brow + wr + ((lane >> 4) * 4);
  const int ccol = bcol + wc + (lane & 15);
  float bv[4];
  if (RELU_BIAS) {
#pragma unroll
    for (int n = 0; n < 4; ++n) bv[n] = bias[ccol + n * 16];
  }
#pragma unroll
  for (int m = 0; m < 4; ++m)
#pragma unroll
    for (int n = 0; n < 4; ++n)
#pragma unroll
      for (int r = 0; r < 4; ++r) {
        float vv = acc[m][n][r];
        if (RELU_BIAS) vv = fmaxf(vv + bv[n], 0.f);
        C[(size_t)(crow + m * 16 + r) * N + ccol + n * 16] = f2bf(vv);
      }
}

// Flash attention. grid = (NQ/128, B*H). block = 256 (4 waves, 32 q-rows each).
// Qp/Kp/Vp are projected bf16 [B*2048, 1024]; head h occupies cols [h*128,(h+1)*128).
// mask[b*NK+k] != 0  =>  key masked (-inf logit). scale = 1/sqrt(D) = 1/32.
__global__ __launch_bounds__(256) void attn_fused(
    const unsigned short* __restrict__ Qp, const unsigned short* __restrict__ Kp,
    const unsigned short* __restrict__ Vp, const int* __restrict__ mask,
    unsigned short* __restrict__ Att) {
  constexpr int DD = 1024, Dh = 128, NK = 2048;
  constexpr int VST = 80;  // padded row stride for Vt/Pl (4-way banks, 16B aligned)
  __shared__ __align__(16) unsigned short lds[64 * 128 + 2 * 128 * VST];
  __shared__ float smask[64];
  unsigned short* Ks = lds;
  unsigned short* Vt = lds + 64 * 128;
  unsigned short* Pl = Vt + 128 * VST;

  const int tid = threadIdx.x, lane = tid & 63, w = tid >> 6;
  const int b = blockIdx.y >> 3, h = blockIdx.y & 7;
  const int q0 = blockIdx.x * 128;
  const unsigned short* Qbase = Qp + ((size_t)b * 2048 + q0) * DD + h * Dh;
  const unsigned short* Kbase = Kp + (size_t)b * 2048 * DD + h * Dh;
  const unsigned short* Vbase = Vp + (size_t)b * 2048 * DD + h * Dh;

  // ---- stage Q tile [128][128] (linear) then hoist frags to regs ----
#pragma unroll
  for (int j = 0; j < 8; ++j) {
    int row = w * 32 + j * 4 + (lane >> 4);
    const unsigned short* g = Qbase + (size_t)row * DD + (lane & 15) * 8;
    gload_lds16(g, lds + w * 4096 + j * 512);
  }
  asm volatile("s_waitcnt vmcnt(0)" ::: "memory");
  __syncthreads();
  s16x8 qf[2][4];
#pragma unroll
  for (int i = 0; i < 2; ++i)
#pragma unroll
    for (int ks = 0; ks < 4; ++ks)
      qf[i][ks] = *(const s16x8*)(lds + (w * 32 + i * 16 + (lane & 15)) * 128 +
                                  ks * 32 + (lane >> 4) * 8);

  f32x4 o[2][8] = {};
  float mrow[2][4], lrow[2][4];
#pragma unroll
  for (int i = 0; i < 2; ++i)
#pragma unroll
    for (int r = 0; r < 4; ++r) { mrow[i][r] = -1e30f; lrow[i][r] = 0.f; }

  for (int kt = 0; kt < NK / 64; ++kt) {
    const int k0 = kt * 64;
    __syncthreads();  // prior iteration's LDS reads done before overwrite
    // stage K [64][128] with XOR-swizzled SOURCE (linear LDS dest)
#pragma unroll
    for (int j = 0; j < 4; ++j) {
      int row = w * 16 + j * 4 + (lane >> 4);
      int cb = (lane & 15) * 16;             // byte chunk within 256B row
      int cbs = cb ^ ((row & 7) << 4);       // involution on bits 4..6
      const unsigned short* g = Kbase + (size_t)(k0 + row) * DD + (cbs >> 1);
      gload_lds16(g, Ks + w * 2048 + j * 512);
    }
    // stage V transposed: Vt[dim][key] (scalar scatter; known bank-conflicted)
#pragma unroll
    for (int rr = 0; rr < 4; ++rr) {
      int vid = rr * 256 + tid;
      int key = vid >> 4;
      int dimb = (vid & 15) * 8;
      s16x8 vv = *(const s16x8*)(Vbase + (size_t)(k0 + key) * DD + dimb);
#pragma unroll
      for (int jj = 0; jj < 8; ++jj)
        Vt[(dimb + jj) * VST + key] = (unsigned short)vv[jj];
    }
    if (tid < 64) smask[tid] = mask[b * NK + k0 + tid] ? -1e30f : 0.0f;
    asm volatile("s_waitcnt vmcnt(0)" ::: "memory");
    __syncthreads();

    // ---- S = (Q K^T)/32 + mask, online softmax, P -> LDS ----
#pragma unroll
    for (int i = 0; i < 2; ++i) {
      f32x4 s[4];
#pragma unroll
      for (int n = 0; n < 4; ++n) {
        f32x4 acc = {};
#pragma unroll
        for (int ks = 0; ks < 4; ++ks) {
          int row = n * 16 + (lane & 15);
          int cb = (ks * 32 + (lane >> 4) * 8) * 2;
          int cbs = cb ^ ((row & 7) << 4);
          s16x8 bf = *(const s16x8*)((const char*)(Ks + row * 128) + cbs);
          acc = __builtin_amdgcn_mfma_f32_16x16x32_bf16(qf[i][ks], bf, acc, 0, 0, 0);
        }
        float ma = smask[n * 16 + (lane & 15)];
#pragma unroll
        for (int r = 0; r < 4; ++r) acc[r] = acc[r] * 0.03125f + ma;
        s[n] = acc;
      }
      float tm[4];
#pragma unroll
      for (int r = 0; r < 4; ++r)
        tm[r] = fmaxf(fmaxf(s[0][r], s[1][r]), fmaxf(s[2][r], s[3][r]));
#pragma unroll
      for (int d = 1; d < 16; d <<= 1)
#pragma unroll
        for (int r = 0; r < 4; ++r)
          tm[r] = fmaxf(tm[r], __shfl_xor(tm[r], d, 64));
      float al[4], rs[4];
#pragma unroll
      for (int r = 0; r < 4; ++r) {
        float mn = fmaxf(mrow[i][r], tm[r]);
        al[r] = __expf(mrow[i][r] - mn);
        mrow[i][r] = mn;
        rs[r] = 0.f;
      }
      const int prow = (w * 32 + i * 16 + (lane >> 4) * 4) * VST + (lane & 15);
#pragma unroll
      for (int n = 0; n < 4; ++n)
#pragma unroll
        for (int r = 0; r < 4; ++r) {
          float p = __expf(s[n][r] - mrow[i][r]);
          rs[r] += p;
          Pl[prow + r * VST + n * 16] = f2bf(p);
        }
#pragma unroll
      for (int d = 1; d < 16; d <<= 1)
#pragma unroll
        for (int r = 0; r < 4; ++r)
          rs[r] += __shfl_xor(rs[r], d, 64);
#pragma unroll
      for (int r = 0; r < 4; ++r)
        lrow[i][r] = lrow[i][r] * al[r] + rs[r];
#pragma unroll
      for (int n = 0; n < 8; ++n)
#pragma unroll
        for (int r = 0; r < 4; ++r)
          o[i][n][r] *= al[r];
    }

    // ---- O += P V (reads only this wave's Pl rows; same-wave LDS order ok) ----
#pragma unroll
    for (int ks2 = 0; ks2 < 2; ++ks2) {
      s16x8 pa[2];
#pragma unroll
      for (int i = 0; i < 2; ++i)
        pa[i] = *(const s16x8*)(Pl + (w * 32 + i * 16 + (lane & 15)) * VST +
                                ks2 * 32 + (lane >> 4) * 8);
#pragma unroll
      for (int n = 0; n < 8; ++n) {
        s16x8 vb = *(const s16x8*)(Vt + (n * 16 + (lane & 15)) * VST +
                                   ks2 * 32 + (lane >> 4) * 8);
#pragma unroll
        for (int i = 0; i < 2; ++i)
          o[i][n] = __builtin_amdgcn_mfma_f32_16x16x32_bf16(pa[i], vb, o[i][n], 0, 0, 0);
      }
    }
  }

  // ---- normalize + write ----
#pragma unroll
  for (int i = 0; i < 2; ++i) {
    float inv[4];
#pragma unroll
    for (int r = 0; r < 4; ++r) {
      float den = lrow[i][r];
      inv[r] = (mrow[i][r] <= -1e29f || den <= 0.f) ? 0.f : 1.f / den;
    }
#pragma unroll
    for (int n = 0; n < 8; ++n)
#pragma unroll
      for (int r = 0; r < 4; ++r) {
        int q = q0 + w * 32 + i * 16 + (lane >> 4) * 4 + r;
        Att[((size_t)b * 2048 + q) * DD + h * Dh + n * 16 + (lane & 15)] =
            f2bf(o[i][n][r] * inv[r]);
      }
  }
}

// out = LayerNorm(X + Y) * g + b. One block per 1024-elem row.
template<int OUT_F32>
__global__ __launch_bounds__(256) void add_ln(
    const unsigned short* __restrict__ X, const unsigned short* __restrict__ Y,
    const float* __restrict__ gam, const float* __restrict__ bet,
    void* __restrict__ out) {
  const int row = blockIdx.x;
  const int tid = threadIdx.x;
  const int lane = tid & 63, w = tid >> 6;
  __shared__ float rbuf[8];
  const size_t base = (size_t)row * 1024 + tid * 4;
  s16x4 xa = *(const s16x4*)(X + base);
  s16x4 yb = *(const s16x4*)(Y + base);
  float x[4];
  float s1 = 0.f, s2 = 0.f;
#pragma unroll
  for (int j = 0; j < 4; ++j) {
    x[j] = bf2f((unsigned short)xa[j]) + bf2f((unsigned short)yb[j]);
    s1 += x[j];
    s2 += x[j] * x[j];
  }
#pragma unroll
  for (int d = 1; d < 64; d <<= 1) {
    s1 += __shfl_xor(s1, d, 64);
    s2 += __shfl_xor(s2, d, 64);
  }
  if (lane == 0) { rbuf[w] = s1; rbuf[4 + w] = s2; }
  __syncthreads();
  float t1 = rbuf[0] + rbuf[1] + rbuf[2] + rbuf[3];
  float t2 = rbuf[4] + rbuf[5] + rbuf[6] + rbuf[7];
  float mu = t1 * (1.f / 1024.f);
  float var = t2 * (1.f / 1024.f) - mu * mu;
  float rstd = rsqrtf(fmaxf(var, 0.f) + 1e-5f);
  float4 g4 = *(const float4*)(gam + tid * 4);
  float4 b4 = *(const float4*)(bet + tid * 4);
  float gg[4] = {g4.x, g4.y, g4.z, g4.w};
  float bb[4] = {b4.x, b4.y, b4.z, b4.w};
  if (OUT_F32) {
    float4 o4;
    o4.x = (x[0] - mu) * rstd * gg[0] + bb[0];
    o4.y = (x[1] - mu) * rstd * gg[1] + bb[1];
    o4.z = (x[2] - mu) * rstd * gg[2] + bb[2];
    o4.w = (x[3] - mu) * rstd * gg[3] + bb[3];
    *(float4*)((float*)out + base) = o4;
  } else {
    s16x4 o;
#pragma unroll
    for (int j = 0; j < 4; ++j)
      o[j] = (short)f2bf((x[j] - mu) * rstd * gg[j] + bb[j]);
    *(s16x4*)((unsigned short*)out + base) = o;
  }
}

extern "C" void kernel_launch(void* const* d_in, const int* in_sizes, int n_in,
                              void* d_out, int out_size, void* d_ws, size_t ws_size,
                              hipStream_t stream) {
  const float* q  = (const float*)d_in[0];
  const float* k  = (const float*)d_in[1];
  const float* v  = (const float*)d_in[2];
  const int* msk  = (const int*)d_in[3];
  const float* Wq = (const float*)d_in[4];
  const float* Wk = (const float*)d_in[5];
  const float* Wv = (const float*)d_in[6];
  const float* Wo = (const float*)d_in[7];
  const float* bo = (const float*)d_in[8];
  const float* g1 = (const float*)d_in[9];
  const float* b1 = (const float*)d_in[10];
  const float* g2 = (const float*)d_in[11];
  const float* b2 = (const float*)d_in[12];
  float* out = (float*)d_out;

  char* ws = (char*)d_ws;
  const size_t S = (size_t)8192 * 1024 * 2;
  unsigned short* qb  = (unsigned short*)(ws + 0 * S);
  unsigned short* kb  = (unsigned short*)(ws + 1 * S);
  unsigned short* vb  = (unsigned short*)(ws + 2 * S);
  unsigned short* qpb = (unsigned short*)(ws + 3 * S);
  unsigned short* kpb = (unsigned short*)(ws + 4 * S);
  unsigned short* vpb = (unsigned short*)(ws + 5 * S);
  unsigned short* attb = qb;  // reuse: q bf16 dead after proj
  unsigned short* h1b  = kb;
  unsigned short* h2b  = vb;
  unsigned short* Wqb = (unsigned short*)(ws + 6 * S);
  unsigned short* Wkb = Wqb + (size_t)1024 * 1024;
  unsigned short* Wvb = Wkb + (size_t)1024 * 1024;
  unsigned short* Wob = Wvb + (size_t)1024 * 1024;

  const int n4big = 8192 * 1024 / 4;
  const int n4w   = 1024 * 1024 / 4;
  cvt_f32_bf16<<<8192, 256, 0, stream>>>(q, qb, n4big);
  cvt_f32_bf16<<<8192, 256, 0, stream>>>(k, kb, n4big);
  cvt_f32_bf16<<<8192, 256, 0, stream>>>(v, vb, n4big);
  cvt_f32_bf16<<<1024, 256, 0, stream>>>(Wq, Wqb, n4w);
  cvt_f32_bf16<<<1024, 256, 0, stream>>>(Wk, Wkb, n4w);
  cvt_f32_bf16<<<1024, 256, 0, stream>>>(Wv, Wvb, n4w);
  cvt_f32_bf16<<<1024, 256, 0, stream>>>(Wo, Wob, n4w);

  dim3 gg(64, 8);
  gemm_bt<0><<<gg, 256, 0, stream>>>(qb, Wqb, qpb, nullptr, 8192, 1024, 1024);
  gemm_bt<0><<<gg, 256, 0, stream>>>(kb, Wkb, kpb, nullptr, 8192, 1024, 1024);
  gemm_bt<0><<<gg, 256, 0, stream>>>(vb, Wvb, vpb, nullptr, 8192, 1024, 1024);

  attn_fused<<<dim3(16, 32), 256, 0, stream>>>(qpb, kpb, vpb, msk, attb);

  add_ln<0><<<8192, 256, 0, stream>>>(qpb, attb, g1, b1, (void*)h1b);
  gemm_bt<1><<<gg, 256, 0, stream>>>(h1b, Wob, h2b, bo, 8192, 1024, 1024);
  add_ln<1><<<8192, 256, 0, stream>>>(h1b, h2b, g2, b2, (void*)out);
}

// Round 2
// 400.308 us; speedup vs baseline: 1.2210x; 1.2210x over previous
//
#include <hip/hip_runtime.h>

// MultiHeadAttn fused block, MI355X/gfx950.
// Pipeline: cvt f32->bf16 -> 3x proj GEMM (bf16 MFMA) -> flash attn -> add+LN
//           -> out GEMM (+bias+relu) -> add+LN -> f32 out.
// Round 2: attn V path rewritten — subtiled LDS layout staged via
// global_load_lds with pre-swizzled source, consumed with ds_read_b64_tr_b16.
// Pl stride 80->72. T13 defer-max.

typedef __attribute__((ext_vector_type(4))) float f32x4;
typedef __attribute__((ext_vector_type(8))) short s16x8;
typedef __attribute__((ext_vector_type(4))) short s16x4;

__device__ __forceinline__ unsigned short f2bf(float f) {
  union { float f; unsigned u; } x; x.f = f;
  unsigned r = x.u + 0x7fffu + ((x.u >> 16) & 1u);
  return (unsigned short)(r >> 16);
}
__device__ __forceinline__ float bf2f(unsigned short h) {
  union { unsigned u; float f; } x; x.u = ((unsigned)h) << 16;
  return x.f;
}

__device__ __forceinline__ void gload_lds16(const void* g, void* l) {
  __builtin_amdgcn_global_load_lds(
      (const __attribute__((address_space(1))) unsigned int*)g,
      (__attribute__((address_space(3))) unsigned int*)l, 16, 0, 0);
}

__device__ __forceinline__ unsigned lds_off(const void* p) {
  return (unsigned)(size_t)(const __attribute__((address_space(3))) void*)p;
}

__global__ __launch_bounds__(256) void cvt_f32_bf16(
    const float* __restrict__ src, unsigned short* __restrict__ dst, int n4) {
  int i = blockIdx.x * blockDim.x + threadIdx.x;
  if (i >= n4) return;
  float4 f = reinterpret_cast<const float4*>(src)[i];
  s16x4 o;
  o[0] = (short)f2bf(f.x); o[1] = (short)f2bf(f.y);
  o[2] = (short)f2bf(f.z); o[3] = (short)f2bf(f.w);
  reinterpret_cast<s16x4*>(dst)[i] = o;
}

// C[M,N] = A[M,K] @ B[N,K]^T, all bf16 (C bf16 out), optional bias+relu epilogue.
// 128x128 tile, BK=32, 4 waves (2x2), 4x4 16x16x32 frags per wave.
template<int RELU_BIAS>
__global__ __launch_bounds__(256) void gemm_bt(
    const unsigned short* __restrict__ A, const unsigned short* __restrict__ B,
    unsigned short* __restrict__ C, const float* __restrict__ bias,
    int M, int N, int K) {
  __shared__ __align__(16) unsigned short As[128 * 32];
  __shared__ __align__(16) unsigned short Bs[128 * 32];
  const int tid = threadIdx.x;
  const int lane = tid & 63;
  const int w = tid >> 6;
  const int brow = blockIdx.x * 128;
  const int bcol = blockIdx.y * 128;
  const int wr = (w >> 1) * 64;
  const int wc = (w & 1) * 64;

  f32x4 acc[4][4] = {};

  const int srow = w * 32 + (lane >> 2);  // + j*16
  const int scol = (lane & 3) * 8;
  const int rfrag = lane & 15;
  const int kfrag = (lane >> 4) * 8;

  for (int k0 = 0; k0 < K; k0 += 32) {
    __syncthreads();
#pragma unroll
    for (int j = 0; j < 2; ++j) {
      const unsigned short* ga = A + (size_t)(brow + srow + j * 16) * K + k0 + scol;
      gload_lds16(ga, As + (w * 1024 + j * 512));
      const unsigned short* gb = B + (size_t)(bcol + srow + j * 16) * K + k0 + scol;
      gload_lds16(gb, Bs + (w * 1024 + j * 512));
    }
    asm volatile("s_waitcnt vmcnt(0)" ::: "memory");
    __syncthreads();
    s16x8 a[4], b[4];
#pragma unroll
    for (int m = 0; m < 4; ++m)
      a[m] = *(const s16x8*)(As + (wr + m * 16 + rfrag) * 32 + kfrag);
#pragma unroll
    for (int n = 0; n < 4; ++n)
      b[n] = *(const s16x8*)(Bs + (wc + n * 16 + rfrag) * 32 + kfrag);
#pragma unroll
    for (int m = 0; m < 4; ++m)
#pragma unroll
      for (int n = 0; n < 4; ++n)
        acc[m][n] = __builtin_amdgcn_mfma_f32_16x16x32_bf16(a[m], b[n], acc[m][n], 0, 0, 0);
  }

  const int crow = brow + wr + ((lane >> 4) * 4);
  const int ccol = bcol + wc + (lane & 15);
  float bv[4];
  if (RELU_BIAS) {
#pragma unroll
    for (int n = 0; n < 4; ++n) bv[n] = bias[ccol + n * 16];
  }
#pragma unroll
  for (int m = 0; m < 4; ++m)
#pragma unroll
    for (int n = 0; n < 4; ++n)
#pragma unroll
      for (int r = 0; r < 4; ++r) {
        float vv = acc[m][n][r];
        if (RELU_BIAS) vv = fmaxf(vv + bv[n], 0.f);
        C[(size_t)(crow + m * 16 + r) * N + ccol + n * 16] = f2bf(vv);
      }
}

// Flash attention. grid = (NQ/128, B*H). block = 256 (4 waves, 32 q-rows each).
// LDS map (u16 elems): Ks [0,8192) row-major [64][128] col-XOR-swizzled;
//                      Vs [8192,16384) subtiled [k/4][d/16][4][16];
//                      Pl [16384,25600) rows stride VST=72.
// Q stage reuses [0,16384) before the k-loop.
__global__ __launch_bounds__(256) void attn_fused(
    const unsigned short* __restrict__ Qp, const unsigned short* __restrict__ Kp,
    const unsigned short* __restrict__ Vp, const int* __restrict__ mask,
    unsigned short* __restrict__ Att) {
  constexpr int DD = 1024, NK = 2048;
  constexpr int VST = 72;
  __shared__ __align__(16) unsigned short lds[25600];
  __shared__ float smask[64];
  unsigned short* Ks = lds;
  unsigned short* Vs = lds + 8192;
  unsigned short* Pl = lds + 16384;

  const int tid = threadIdx.x, lane = tid & 63, w = tid >> 6;
  const int b = blockIdx.y >> 3, h = blockIdx.y & 7;
  const int q0 = blockIdx.x * 128;
  const unsigned short* Qbase = Qp + ((size_t)b * 2048 + q0) * DD + h * 128;
  const unsigned short* Kbase = Kp + (size_t)b * 2048 * DD + h * 128;
  const unsigned short* Vbase = Vp + (size_t)b * 2048 * DD + h * 128;

  // ---- stage Q tile [128][128] (linear) then hoist frags to regs ----
#pragma unroll
  for (int j = 0; j < 8; ++j) {
    int row = w * 32 + j * 4 + (lane >> 4);
    const unsigned short* g = Qbase + (size_t)row * DD + (lane & 15) * 8;
    gload_lds16(g, lds + w * 4096 + j * 512);
  }
  asm volatile("s_waitcnt vmcnt(0)" ::: "memory");
  __syncthreads();
  s16x8 qf[2][4];
#pragma unroll
  for (int i = 0; i < 2; ++i)
#pragma unroll
    for (int ks = 0; ks < 4; ++ks)
      qf[i][ks] = *(const s16x8*)(lds + (w * 32 + i * 16 + (lane & 15)) * 128 +
                                  ks * 32 + (lane >> 4) * 8);

  const unsigned vb0 = lds_off(Vs);

  f32x4 o[2][8] = {};
  float mrow[2][4], lrow[2][4];
#pragma unroll
  for (int i = 0; i < 2; ++i)
#pragma unroll
    for (int r = 0; r < 4; ++r) { mrow[i][r] = -1e30f; lrow[i][r] = 0.f; }

  for (int kt = 0; kt < NK / 64; ++kt) {
    const int k0 = kt * 64;
    __syncthreads();  // prior iteration's LDS reads done before overwrite
    // stage K [64][128] with XOR-swizzled SOURCE (linear LDS dest)
#pragma unroll
    for (int j = 0; j < 4; ++j) {
      int row = w * 16 + j * 4 + (lane >> 4);
      int cb = (lane & 15) * 16;             // byte chunk within 256B row
      int cbs = cb ^ ((row & 7) << 4);       // involution on bits 4..6
      const unsigned short* g = Kbase + (size_t)(k0 + row) * DD + (cbs >> 1);
      gload_lds16(g, Ks + w * 2048 + j * 512);
    }
    // stage V into subtile layout [k/4][d/16][4][16] via pre-swizzled source:
    // 16B slot s covers subtiled elems [8s,8s+8): k=(s>>6)*4+((s>>1)&3),
    // d=((s>>3)&7)*16+(s&1)*8.
#pragma unroll
    for (int it = 0; it < 4; ++it) {
      int s = w * 256 + it * 64 + lane;
      int kk = ((s >> 6) << 2) | ((s >> 1) & 3);
      int dd = (((s >> 3) & 7) << 4) | ((s & 1) << 3);
      const unsigned short* g = Vbase + (size_t)(k0 + kk) * DD + dd;
      gload_lds16(g, Vs + (size_t)(w * 256 + it * 64) * 8);
    }
    if (tid < 64) smask[tid] = mask[b * NK + k0 + tid] ? -1e30f : 0.0f;
    asm volatile("s_waitcnt vmcnt(0)" ::: "memory");
    __syncthreads();

    // ---- S = (Q K^T)/32 + mask, online softmax, P -> LDS ----
#pragma unroll
    for (int i = 0; i < 2; ++i) {
      f32x4 s[4];
#pragma unroll
      for (int n = 0; n < 4; ++n) {
        f32x4 acc = {};
#pragma unroll
        for (int ks = 0; ks < 4; ++ks) {
          int row = n * 16 + (lane & 15);
          int cb = (ks * 32 + (lane >> 4) * 8) * 2;
          int cbs = cb ^ ((row & 7) << 4);
          s16x8 bf = *(const s16x8*)((const char*)(Ks + row * 128) + cbs);
          acc = __builtin_amdgcn_mfma_f32_16x16x32_bf16(qf[i][ks], bf, acc, 0, 0, 0);
        }
        float ma = smask[n * 16 + (lane & 15)];
#pragma unroll
        for (int r = 0; r < 4; ++r) acc[r] = acc[r] * 0.03125f + ma;
        s[n] = acc;
      }
      float tm[4];
#pragma unroll
      for (int r = 0; r < 4; ++r)
        tm[r] = fmaxf(fmaxf(s[0][r], s[1][r]), fmaxf(s[2][r], s[3][r]));
#pragma unroll
      for (int d = 1; d < 16; d <<= 1)
#pragma unroll
        for (int r = 0; r < 4; ++r)
          tm[r] = fmaxf(tm[r], __shfl_xor(tm[r], d, 64));
      // T13 defer-max: skip m-update + O-rescale if growth <= 8 for all rows.
      float mx = fmaxf(fmaxf(tm[0] - mrow[i][0], tm[1] - mrow[i][1]),
                       fmaxf(tm[2] - mrow[i][2], tm[3] - mrow[i][3]));
      const bool up = !__all(mx <= 8.f);
      float al[4], rs[4];
#pragma unroll
      for (int r = 0; r < 4; ++r) {
        float mn = up ? fmaxf(mrow[i][r], tm[r]) : mrow[i][r];
        al[r] = __expf(mrow[i][r] - mn);  // ==1 when !up
        mrow[i][r] = mn;
        rs[r] = 0.f;
      }
      const int prow = (w * 32 + i * 16 + (lane >> 4) * 4) * VST + (lane & 15);
#pragma unroll
      for (int n = 0; n < 4; ++n)
#pragma unroll
        for (int r = 0; r < 4; ++r) {
          float p = __expf(s[n][r] - mrow[i][r]);
          rs[r] += p;
          Pl[prow + r * VST + n * 16] = f2bf(p);
        }
#pragma unroll
      for (int d = 1; d < 16; d <<= 1)
#pragma unroll
        for (int r = 0; r < 4; ++r)
          rs[r] += __shfl_xor(rs[r], d, 64);
#pragma unroll
      for (int r = 0; r < 4; ++r)
        lrow[i][r] = lrow[i][r] * al[r] + rs[r];
      if (up) {
#pragma unroll
        for (int n = 0; n < 8; ++n)
#pragma unroll
          for (int r = 0; r < 4; ++r)
            o[i][n][r] *= al[r];
      }
    }

    // ---- O += P V: V via ds_read_b64_tr_b16 from subtiled Vs ----
#pragma unroll
    for (int ks2 = 0; ks2 < 2; ++ks2) {
      s16x8 pa[2];
#pragma unroll
      for (int i = 0; i < 2; ++i)
        pa[i] = *(const s16x8*)(Pl + (w * 32 + i * 16 + (lane & 15)) * VST +
                                ks2 * 32 + (lane >> 4) * 8);
      // per-lane addr: subtile(base k = ks2*32 + (lane>>4)*8) + (lane&15)*8B;
      // offset:1024 walks to keys +4 (next k-subtile).
      const unsigned base =
          vb0 + ks2 * 8192 + (lane >> 4) * 2048 + (lane & 15) * 8;
      s16x4 vlo[8], vhi[8];
#pragma unroll
      for (int n = 0; n < 8; ++n) {
        asm volatile("ds_read_b64_tr_b16 %0, %2\n\t"
                     "ds_read_b64_tr_b16 %1, %2 offset:1024"
                     : "=v"(vlo[n]), "=v"(vhi[n])
                     : "v"(base + n * 128)
                     : "memory");
      }
      asm volatile("s_waitcnt lgkmcnt(0)" ::: "memory");
      __builtin_amdgcn_sched_barrier(0);
#pragma unroll
      for (int n = 0; n < 8; ++n) {
        s16x8 vv;
#pragma unroll
        for (int j = 0; j < 4; ++j) { vv[j] = vlo[n][j]; vv[4 + j] = vhi[n][j]; }
#pragma unroll
        for (int i = 0; i < 2; ++i)
          o[i][n] = __builtin_amdgcn_mfma_f32_16x16x32_bf16(pa[i], vv, o[i][n], 0, 0, 0);
      }
    }
  }

  // ---- normalize + write ----
#pragma unroll
  for (int i = 0; i < 2; ++i) {
    float inv[4];
#pragma unroll
    for (int r = 0; r < 4; ++r) {
      float den = lrow[i][r];
      inv[r] = (mrow[i][r] <= -1e29f || den <= 0.f) ? 0.f : 1.f / den;
    }
#pragma unroll
    for (int n = 0; n < 8; ++n)
#pragma unroll
      for (int r = 0; r < 4; ++r) {
        int q = q0 + w * 32 + i * 16 + (lane >> 4) * 4 + r;
        Att[((size_t)b * 2048 + q) * DD + h * 128 + n * 16 + (lane & 15)] =
            f2bf(o[i][n][r] * inv[r]);
      }
  }
}

// out = LayerNorm(X + Y) * g + b. One block per 1024-elem row.
template<int OUT_F32>
__global__ __launch_bounds__(256) void add_ln(
    const unsigned short* __restrict__ X, const unsigned short* __restrict__ Y,
    const float* __restrict__ gam, const float* __restrict__ bet,
    void* __restrict__ out) {
  const int row = blockIdx.x;
  const int tid = threadIdx.x;
  const int lane = tid & 63, w = tid >> 6;
  __shared__ float rbuf[8];
  const size_t base = (size_t)row * 1024 + tid * 4;
  s16x4 xa = *(const s16x4*)(X + base);
  s16x4 yb = *(const s16x4*)(Y + base);
  float x[4];
  float s1 = 0.f, s2 = 0.f;
#pragma unroll
  for (int j = 0; j < 4; ++j) {
    x[j] = bf2f((unsigned short)xa[j]) + bf2f((unsigned short)yb[j]);
    s1 += x[j];
    s2 += x[j] * x[j];
  }
#pragma unroll
  for (int d = 1; d < 64; d <<= 1) {
    s1 += __shfl_xor(s1, d, 64);
    s2 += __shfl_xor(s2, d, 64);
  }
  if (lane == 0) { rbuf[w] = s1; rbuf[4 + w] = s2; }
  __syncthreads();
  float t1 = rbuf[0] + rbuf[1] + rbuf[2] + rbuf[3];
  float t2 = rbuf[4] + rbuf[5] + rbuf[6] + rbuf[7];
  float mu = t1 * (1.f / 1024.f);
  float var = t2 * (1.f / 1024.f) - mu * mu;
  float rstd = rsqrtf(fmaxf(var, 0.f) + 1e-5f);
  float4 g4 = *(const float4*)(gam + tid * 4);
  float4 b4 = *(const float4*)(bet + tid * 4);
  float gg[4] = {g4.x, g4.y, g4.z, g4.w};
  float bb[4] = {b4.x, b4.y, b4.z, b4.w};
  if (OUT_F32) {
    float4 o4;
    o4.x = (x[0] - mu) * rstd * gg[0] + bb[0];
    o4.y = (x[1] - mu) * rstd * gg[1] + bb[1];
    o4.z = (x[2] - mu) * rstd * gg[2] + bb[2];
    o4.w = (x[3] - mu) * rstd * gg[3] + bb[3];
    *(float4*)((float*)out + base) = o4;
  } else {
    s16x4 o;
#pragma unroll
    for (int j = 0; j < 4; ++j)
      o[j] = (short)f2bf((x[j] - mu) * rstd * gg[j] + bb[j]);
    *(s16x4*)((unsigned short*)out + base) = o;
  }
}

extern "C" void kernel_launch(void* const* d_in, const int* in_sizes, int n_in,
                              void* d_out, int out_size, void* d_ws, size_t ws_size,
                              hipStream_t stream) {
  const float* q  = (const float*)d_in[0];
  const float* k  = (const float*)d_in[1];
  const float* v  = (const float*)d_in[2];
  const int* msk  = (const int*)d_in[3];
  const float* Wq = (const float*)d_in[4];
  const float* Wk = (const float*)d_in[5];
  const float* Wv = (const float*)d_in[6];
  const float* Wo = (const float*)d_in[7];
  const float* bo = (const float*)d_in[8];
  const float* g1 = (const float*)d_in[9];
  const float* b1 = (const float*)d_in[10];
  const float* g2 = (const float*)d_in[11];
  const float* b2 = (const float*)d_in[12];
  float* out = (float*)d_out;

  char* ws = (char*)d_ws;
  const size_t S = (size_t)8192 * 1024 * 2;
  unsigned short* qb  = (unsigned short*)(ws + 0 * S);
  unsigned short* kb  = (unsigned short*)(ws + 1 * S);
  unsigned short* vb  = (unsigned short*)(ws + 2 * S);
  unsigned short* qpb = (unsigned short*)(ws + 3 * S);
  unsigned short* kpb = (unsigned short*)(ws + 4 * S);
  unsigned short* vpb = (unsigned short*)(ws + 5 * S);
  unsigned short* attb = qb;  // reuse: q bf16 dead after proj
  unsigned short* h1b  = kb;
  unsigned short* h2b  = vb;
  unsigned short* Wqb = (unsigned short*)(ws + 6 * S);
  unsigned short* Wkb = Wqb + (size_t)1024 * 1024;
  unsigned short* Wvb = Wkb + (size_t)1024 * 1024;
  unsigned short* Wob = Wvb + (size_t)1024 * 1024;

  const int n4big = 8192 * 1024 / 4;
  const int n4w   = 1024 * 1024 / 4;
  cvt_f32_bf16<<<8192, 256, 0, stream>>>(q, qb, n4big);
  cvt_f32_bf16<<<8192, 256, 0, stream>>>(k, kb, n4big);
  cvt_f32_bf16<<<8192, 256, 0, stream>>>(v, vb, n4big);
  cvt_f32_bf16<<<1024, 256, 0, stream>>>(Wq, Wqb, n4w);
  cvt_f32_bf16<<<1024, 256, 0, stream>>>(Wk, Wkb, n4w);
  cvt_f32_bf16<<<1024, 256, 0, stream>>>(Wv, Wvb, n4w);
  cvt_f32_bf16<<<1024, 256, 0, stream>>>(Wo, Wob, n4w);

  dim3 gg(64, 8);
  gemm_bt<0><<<gg, 256, 0, stream>>>(qb, Wqb, qpb, nullptr, 8192, 1024, 1024);
  gemm_bt<0><<<gg, 256, 0, stream>>>(kb, Wkb, kpb, nullptr, 8192, 1024, 1024);
  gemm_bt<0><<<gg, 256, 0, stream>>>(vb, Wvb, vpb, nullptr, 8192, 1024, 1024);

  attn_fused<<<dim3(16, 32), 256, 0, stream>>>(qpb, kpb, vpb, msk, attb);

  add_ln<0><<<8192, 256, 0, stream>>>(qpb, attb, g1, b1, (void*)h1b);
  gemm_bt<1><<<gg, 256, 0, stream>>>(h1b, Wob, h2b, bo, 8192, 1024, 1024);
  add_ln<1><<<8192, 256, 0, stream>>>(h1b, h2b, g2, b2, (void*)out);
}

// Round 3
// 353.274 us; speedup vs baseline: 1.3836x; 1.1331x over previous
//
#include <hip/hip_runtime.h>

// MultiHeadAttn fused block, MI355X/gfx950.
// Round 3: attn occupancy fix — QBLK=64 per block (was 128), 1D grid 1024,
// 4 blocks/CU via __launch_bounds__(256,4), XCD-aware bh mapping (each XCD
// owns 4 heads -> KV fits its 4MB L2).

typedef __attribute__((ext_vector_type(4))) float f32x4;
typedef __attribute__((ext_vector_type(8))) short s16x8;
typedef __attribute__((ext_vector_type(4))) short s16x4;

__device__ __forceinline__ unsigned short f2bf(float f) {
  union { float f; unsigned u; } x; x.f = f;
  unsigned r = x.u + 0x7fffu + ((x.u >> 16) & 1u);
  return (unsigned short)(r >> 16);
}
__device__ __forceinline__ float bf2f(unsigned short h) {
  union { unsigned u; float f; } x; x.u = ((unsigned)h) << 16;
  return x.f;
}

__device__ __forceinline__ void gload_lds16(const void* g, void* l) {
  __builtin_amdgcn_global_load_lds(
      (const __attribute__((address_space(1))) unsigned int*)g,
      (__attribute__((address_space(3))) unsigned int*)l, 16, 0, 0);
}

__device__ __forceinline__ unsigned lds_off(const void* p) {
  return (unsigned)(size_t)(const __attribute__((address_space(3))) void*)p;
}

__global__ __launch_bounds__(256) void cvt_f32_bf16(
    const float* __restrict__ src, unsigned short* __restrict__ dst, int n4) {
  int i = blockIdx.x * blockDim.x + threadIdx.x;
  if (i >= n4) return;
  float4 f = reinterpret_cast<const float4*>(src)[i];
  s16x4 o;
  o[0] = (short)f2bf(f.x); o[1] = (short)f2bf(f.y);
  o[2] = (short)f2bf(f.z); o[3] = (short)f2bf(f.w);
  reinterpret_cast<s16x4*>(dst)[i] = o;
}

// C[M,N] = A[M,K] @ B[N,K]^T, all bf16 (C bf16 out), optional bias+relu epilogue.
// 128x128 tile, BK=32, 4 waves (2x2), 4x4 16x16x32 frags per wave.
template<int RELU_BIAS>
__global__ __launch_bounds__(256) void gemm_bt(
    const unsigned short* __restrict__ A, const unsigned short* __restrict__ B,
    unsigned short* __restrict__ C, const float* __restrict__ bias,
    int M, int N, int K) {
  __shared__ __align__(16) unsigned short As[128 * 32];
  __shared__ __align__(16) unsigned short Bs[128 * 32];
  const int tid = threadIdx.x;
  const int lane = tid & 63;
  const int w = tid >> 6;
  const int brow = blockIdx.x * 128;
  const int bcol = blockIdx.y * 128;
  const int wr = (w >> 1) * 64;
  const int wc = (w & 1) * 64;

  f32x4 acc[4][4] = {};

  const int srow = w * 32 + (lane >> 2);  // + j*16
  const int scol = (lane & 3) * 8;
  const int rfrag = lane & 15;
  const int kfrag = (lane >> 4) * 8;

  for (int k0 = 0; k0 < K; k0 += 32) {
    __syncthreads();
#pragma unroll
    for (int j = 0; j < 2; ++j) {
      const unsigned short* ga = A + (size_t)(brow + srow + j * 16) * K + k0 + scol;
      gload_lds16(ga, As + (w * 1024 + j * 512));
      const unsigned short* gb = B + (size_t)(bcol + srow + j * 16) * K + k0 + scol;
      gload_lds16(gb, Bs + (w * 1024 + j * 512));
    }
    asm volatile("s_waitcnt vmcnt(0)" ::: "memory");
    __syncthreads();
    s16x8 a[4], b[4];
#pragma unroll
    for (int m = 0; m < 4; ++m)
      a[m] = *(const s16x8*)(As + (wr + m * 16 + rfrag) * 32 + kfrag);
#pragma unroll
    for (int n = 0; n < 4; ++n)
      b[n] = *(const s16x8*)(Bs + (wc + n * 16 + rfrag) * 32 + kfrag);
#pragma unroll
    for (int m = 0; m < 4; ++m)
#pragma unroll
      for (int n = 0; n < 4; ++n)
        acc[m][n] = __builtin_amdgcn_mfma_f32_16x16x32_bf16(a[m], b[n], acc[m][n], 0, 0, 0);
  }

  const int crow = brow + wr + ((lane >> 4) * 4);
  const int ccol = bcol + wc + (lane & 15);
  float bv[4];
  if (RELU_BIAS) {
#pragma unroll
    for (int n = 0; n < 4; ++n) bv[n] = bias[ccol + n * 16];
  }
#pragma unroll
  for (int m = 0; m < 4; ++m)
#pragma unroll
    for (int n = 0; n < 4; ++n)
#pragma unroll
      for (int r = 0; r < 4; ++r) {
        float vv = acc[m][n][r];
        if (RELU_BIAS) vv = fmaxf(vv + bv[n], 0.f);
        C[(size_t)(crow + m * 16 + r) * N + ccol + n * 16] = f2bf(vv);
      }
}

// Flash attention. 1D grid 1024 blocks (32 q-tiles x 32 bh), 256 threads
// (4 waves, 16 q-rows each). XCD-aware id remap: xcd = L&7 owns bh in
// [4*xcd, 4*xcd+4) so its KV working set (4MB) fits one L2.
// LDS map (u16): Ks [0,8192) row-major [64][128] col-XOR-swizzled;
//                Vs [8192,16384) subtiled [k/4][d/16][4][16];
//                Pl [16384,20992) rows stride VST=72.
// Q stage reuses Ks before the k-loop.
__global__ __launch_bounds__(256, 4) void attn_fused(
    const unsigned short* __restrict__ Qp, const unsigned short* __restrict__ Kp,
    const unsigned short* __restrict__ Vp, const int* __restrict__ mask,
    unsigned short* __restrict__ Att) {
  constexpr int DD = 1024, NK = 2048;
  constexpr int VST = 72;
  __shared__ __align__(16) unsigned short lds[20992];
  __shared__ float smask[64];
  unsigned short* Ks = lds;
  unsigned short* Vs = lds + 8192;
  unsigned short* Pl = lds + 16384;

  const int tid = threadIdx.x, lane = tid & 63, w = tid >> 6;
  const int L = blockIdx.x;
  const int bh = (L & 7) * 4 + (L >> 8);   // 4 heads per XCD
  const int qt = (L >> 3) & 31;
  const int b = bh >> 3, h = bh & 7;
  const int q0 = qt * 64;
  const unsigned short* Qbase = Qp + ((size_t)b * 2048 + q0) * DD + h * 128;
  const unsigned short* Kbase = Kp + (size_t)b * 2048 * DD + h * 128;
  const unsigned short* Vbase = Vp + (size_t)b * 2048 * DD + h * 128;

  // ---- stage Q tile [64][128] (linear, in Ks area) then hoist frags ----
#pragma unroll
  for (int j = 0; j < 4; ++j) {
    int row = w * 16 + j * 4 + (lane >> 4);
    const unsigned short* g = Qbase + (size_t)row * DD + (lane & 15) * 8;
    gload_lds16(g, lds + w * 2048 + j * 512);
  }
  asm volatile("s_waitcnt vmcnt(0)" ::: "memory");
  __syncthreads();
  s16x8 qf[4];
#pragma unroll
  for (int ks = 0; ks < 4; ++ks)
    qf[ks] = *(const s16x8*)(lds + (w * 16 + (lane & 15)) * 128 +
                             ks * 32 + (lane >> 4) * 8);

  const unsigned vb0 = lds_off(Vs);

  f32x4 o[8] = {};
  float mrow[4], lrow[4];
#pragma unroll
  for (int r = 0; r < 4; ++r) { mrow[r] = -1e30f; lrow[r] = 0.f; }

  for (int kt = 0; kt < NK / 64; ++kt) {
    const int k0 = kt * 64;
    __syncthreads();  // prior iteration's LDS reads done before overwrite
    // stage K [64][128] with XOR-swizzled SOURCE (linear LDS dest)
#pragma unroll
    for (int j = 0; j < 4; ++j) {
      int row = w * 16 + j * 4 + (lane >> 4);
      int cb = (lane & 15) * 16;             // byte chunk within 256B row
      int cbs = cb ^ ((row & 7) << 4);       // involution on bits 4..6
      const unsigned short* g = Kbase + (size_t)(k0 + row) * DD + (cbs >> 1);
      gload_lds16(g, Ks + w * 2048 + j * 512);
    }
    // stage V into subtile layout [k/4][d/16][4][16] via pre-swizzled source:
    // 16B slot s covers subtiled elems [8s,8s+8): k=(s>>6)*4+((s>>1)&3),
    // d=((s>>3)&7)*16+(s&1)*8.
#pragma unroll
    for (int it = 0; it < 4; ++it) {
      int s = w * 256 + it * 64 + lane;
      int kk = ((s >> 6) << 2) | ((s >> 1) & 3);
      int dd = (((s >> 3) & 7) << 4) | ((s & 1) << 3);
      const unsigned short* g = Vbase + (size_t)(k0 + kk) * DD + dd;
      gload_lds16(g, Vs + (size_t)(w * 256 + it * 64) * 8);
    }
    if (tid < 64) smask[tid] = mask[b * NK + k0 + tid] ? -1e30f : 0.0f;
    asm volatile("s_waitcnt vmcnt(0)" ::: "memory");
    __syncthreads();

    // ---- S = (Q K^T)/32 + mask, online softmax, P -> LDS ----
    f32x4 s[4];
#pragma unroll
    for (int n = 0; n < 4; ++n) {
      f32x4 acc = {};
#pragma unroll
      for (int ks = 0; ks < 4; ++ks) {
        int row = n * 16 + (lane & 15);
        int cb = (ks * 32 + (lane >> 4) * 8) * 2;
        int cbs = cb ^ ((row & 7) << 4);
        s16x8 bf = *(const s16x8*)((const char*)(Ks + row * 128) + cbs);
        acc = __builtin_amdgcn_mfma_f32_16x16x32_bf16(qf[ks], bf, acc, 0, 0, 0);
      }
      float ma = smask[n * 16 + (lane & 15)];
#pragma unroll
      for (int r = 0; r < 4; ++r) acc[r] = acc[r] * 0.03125f + ma;
      s[n] = acc;
    }
    float tm[4];
#pragma unroll
    for (int r = 0; r < 4; ++r)
      tm[r] = fmaxf(fmaxf(s[0][r], s[1][r]), fmaxf(s[2][r], s[3][r]));
#pragma unroll
    for (int d = 1; d < 16; d <<= 1)
#pragma unroll
      for (int r = 0; r < 4; ++r)
        tm[r] = fmaxf(tm[r], __shfl_xor(tm[r], d, 64));
    // T13 defer-max: skip m-update + O-rescale if growth <= 8 for all rows.
    float mx = fmaxf(fmaxf(tm[0] - mrow[0], tm[1] - mrow[1]),
                     fmaxf(tm[2] - mrow[2], tm[3] - mrow[3]));
    const bool up = !__all(mx <= 8.f);
    float al[4], rs[4];
#pragma unroll
    for (int r = 0; r < 4; ++r) {
      float mn = up ? fmaxf(mrow[r], tm[r]) : mrow[r];
      al[r] = __expf(mrow[r] - mn);  // ==1 when !up
      mrow[r] = mn;
      rs[r] = 0.f;
    }
    const int prow = (w * 16 + (lane >> 4) * 4) * VST + (lane & 15);
#pragma unroll
    for (int n = 0; n < 4; ++n)
#pragma unroll
      for (int r = 0; r < 4; ++r) {
        float p = __expf(s[n][r] - mrow[r]);
        rs[r] += p;
        Pl[prow + r * VST + n * 16] = f2bf(p);
      }
#pragma unroll
    for (int d = 1; d < 16; d <<= 1)
#pragma unroll
      for (int r = 0; r < 4; ++r)
        rs[r] += __shfl_xor(rs[r], d, 64);
#pragma unroll
    for (int r = 0; r < 4; ++r)
      lrow[r] = lrow[r] * al[r] + rs[r];
    if (up) {
#pragma unroll
      for (int n = 0; n < 8; ++n)
#pragma unroll
        for (int r = 0; r < 4; ++r)
          o[n][r] *= al[r];
    }

    // ---- O += P V: V via ds_read_b64_tr_b16 from subtiled Vs ----
#pragma unroll
    for (int ks2 = 0; ks2 < 2; ++ks2) {
      s16x8 pa = *(const s16x8*)(Pl + (w * 16 + (lane & 15)) * VST +
                                 ks2 * 32 + (lane >> 4) * 8);
      // per-lane addr: subtile(base k = ks2*32 + (lane>>4)*8) + (lane&15)*8B;
      // offset:1024 walks to keys +4 (next k-subtile).
      const unsigned base =
          vb0 + ks2 * 8192 + (lane >> 4) * 2048 + (lane & 15) * 8;
      s16x4 vlo[8], vhi[8];
#pragma unroll
      for (int n = 0; n < 8; ++n) {
        asm volatile("ds_read_b64_tr_b16 %0, %2\n\t"
                     "ds_read_b64_tr_b16 %1, %2 offset:1024"
                     : "=v"(vlo[n]), "=v"(vhi[n])
                     : "v"(base + n * 128)
                     : "memory");
      }
      asm volatile("s_waitcnt lgkmcnt(0)" ::: "memory");
      __builtin_amdgcn_sched_barrier(0);
#pragma unroll
      for (int n = 0; n < 8; ++n) {
        s16x8 vv;
#pragma unroll
        for (int j = 0; j < 4; ++j) { vv[j] = vlo[n][j]; vv[4 + j] = vhi[n][j]; }
        o[n] = __builtin_amdgcn_mfma_f32_16x16x32_bf16(pa, vv, o[n], 0, 0, 0);
      }
    }
  }

  // ---- normalize + write ----
  float inv[4];
#pragma unroll
  for (int r = 0; r < 4; ++r) {
    float den = lrow[r];
    inv[r] = (mrow[r] <= -1e29f || den <= 0.f) ? 0.f : 1.f / den;
  }
#pragma unroll
  for (int n = 0; n < 8; ++n)
#pragma unroll
    for (int r = 0; r < 4; ++r) {
      int q = q0 + w * 16 + (lane >> 4) * 4 + r;
      Att[((size_t)b * 2048 + q) * DD + h * 128 + n * 16 + (lane & 15)] =
          f2bf(o[n][r] * inv[r]);
    }
}

// out = LayerNorm(X + Y) * g + b. One block per 1024-elem row.
template<int OUT_F32>
__global__ __launch_bounds__(256) void add_ln(
    const unsigned short* __restrict__ X, const unsigned short* __restrict__ Y,
    const float* __restrict__ gam, const float* __restrict__ bet,
    void* __restrict__ out) {
  const int row = blockIdx.x;
  const int tid = threadIdx.x;
  const int lane = tid & 63, w = tid >> 6;
  __shared__ float rbuf[8];
  const size_t base = (size_t)row * 1024 + tid * 4;
  s16x4 xa = *(const s16x4*)(X + base);
  s16x4 yb = *(const s16x4*)(Y + base);
  float x[4];
  float s1 = 0.f, s2 = 0.f;
#pragma unroll
  for (int j = 0; j < 4; ++j) {
    x[j] = bf2f((unsigned short)xa[j]) + bf2f((unsigned short)yb[j]);
    s1 += x[j];
    s2 += x[j] * x[j];
  }
#pragma unroll
  for (int d = 1; d < 64; d <<= 1) {
    s1 += __shfl_xor(s1, d, 64);
    s2 += __shfl_xor(s2, d, 64);
  }
  if (lane == 0) { rbuf[w] = s1; rbuf[4 + w] = s2; }
  __syncthreads();
  float t1 = rbuf[0] + rbuf[1] + rbuf[2] + rbuf[3];
  float t2 = rbuf[4] + rbuf[5] + rbuf[6] + rbuf[7];
  float mu = t1 * (1.f / 1024.f);
  float var = t2 * (1.f / 1024.f) - mu * mu;
  float rstd = rsqrtf(fmaxf(var, 0.f) + 1e-5f);
  float4 g4 = *(const float4*)(gam + tid * 4);
  float4 b4 = *(const float4*)(bet + tid * 4);
  float gg[4] = {g4.x, g4.y, g4.z, g4.w};
  float bb[4] = {b4.x, b4.y, b4.z, b4.w};
  if (OUT_F32) {
    float4 o4;
    o4.x = (x[0] - mu) * rstd * gg[0] + bb[0];
    o4.y = (x[1] - mu) * rstd * gg[1] + bb[1];
    o4.z = (x[2] - mu) * rstd * gg[2] + bb[2];
    o4.w = (x[3] - mu) * rstd * gg[3] + bb[3];
    *(float4*)((float*)out + base) = o4;
  } else {
    s16x4 o;
#pragma unroll
    for (int j = 0; j < 4; ++j)
      o[j] = (short)f2bf((x[j] - mu) * rstd * gg[j] + bb[j]);
    *(s16x4*)((unsigned short*)out + base) = o;
  }
}

extern "C" void kernel_launch(void* const* d_in, const int* in_sizes, int n_in,
                              void* d_out, int out_size, void* d_ws, size_t ws_size,
                              hipStream_t stream) {
  const float* q  = (const float*)d_in[0];
  const float* k  = (const float*)d_in[1];
  const float* v  = (const float*)d_in[2];
  const int* msk  = (const int*)d_in[3];
  const float* Wq = (const float*)d_in[4];
  const float* Wk = (const float*)d_in[5];
  const float* Wv = (const float*)d_in[6];
  const float* Wo = (const float*)d_in[7];
  const float* bo = (const float*)d_in[8];
  const float* g1 = (const float*)d_in[9];
  const float* b1 = (const float*)d_in[10];
  const float* g2 = (const float*)d_in[11];
  const float* b2 = (const float*)d_in[12];
  float* out = (float*)d_out;

  char* ws = (char*)d_ws;
  const size_t S = (size_t)8192 * 1024 * 2;
  unsigned short* qb  = (unsigned short*)(ws + 0 * S);
  unsigned short* kb  = (unsigned short*)(ws + 1 * S);
  unsigned short* vb  = (unsigned short*)(ws + 2 * S);
  unsigned short* qpb = (unsigned short*)(ws + 3 * S);
  unsigned short* kpb = (unsigned short*)(ws + 4 * S);
  unsigned short* vpb = (unsigned short*)(ws + 5 * S);
  unsigned short* attb = qb;  // reuse: q bf16 dead after proj
  unsigned short* h1b  = kb;
  unsigned short* h2b  = vb;
  unsigned short* Wqb = (unsigned short*)(ws + 6 * S);
  unsigned short* Wkb = Wqb + (size_t)1024 * 1024;
  unsigned short* Wvb = Wkb + (size_t)1024 * 1024;
  unsigned short* Wob = Wvb + (size_t)1024 * 1024;

  const int n4big = 8192 * 1024 / 4;
  const int n4w   = 1024 * 1024 / 4;
  cvt_f32_bf16<<<8192, 256, 0, stream>>>(q, qb, n4big);
  cvt_f32_bf16<<<8192, 256, 0, stream>>>(k, kb, n4big);
  cvt_f32_bf16<<<8192, 256, 0, stream>>>(v, vb, n4big);
  cvt_f32_bf16<<<1024, 256, 0, stream>>>(Wq, Wqb, n4w);
  cvt_f32_bf16<<<1024, 256, 0, stream>>>(Wk, Wkb, n4w);
  cvt_f32_bf16<<<1024, 256, 0, stream>>>(Wv, Wvb, n4w);
  cvt_f32_bf16<<<1024, 256, 0, stream>>>(Wo, Wob, n4w);

  dim3 gg(64, 8);
  gemm_bt<0><<<gg, 256, 0, stream>>>(qb, Wqb, qpb, nullptr, 8192, 1024, 1024);
  gemm_bt<0><<<gg, 256, 0, stream>>>(kb, Wkb, kpb, nullptr, 8192, 1024, 1024);
  gemm_bt<0><<<gg, 256, 0, stream>>>(vb, Wvb, vpb, nullptr, 8192, 1024, 1024);

  attn_fused<<<1024, 256, 0, stream>>>(qpb, kpb, vpb, msk, attb);

  add_ln<0><<<8192, 256, 0, stream>>>(qpb, attb, g1, b1, (void*)h1b);
  gemm_bt<1><<<gg, 256, 0, stream>>>(h1b, Wob, h2b, bo, 8192, 1024, 1024);
  add_ln<1><<<8192, 256, 0, stream>>>(h1b, h2b, g2, b2, (void*)out);
}